// Round 4
// baseline (3358.312 us; speedup 1.0000x reference)
//
#include <hip/hip_runtime.h>

// B=8, S=2048, D_MODEL=1024, HEAD_DIM=64, NUM_HEADS=16 (all heads identical).
// out = softmax((X Wq)(X Wk)^T / 8) (X Wv) @ Wo_sum + bo, Wo_sum[d,j] = sum_h Wo[h*64+d, j].
// Round 4: same compute as round 3 (two independent impls agreed to 0.002 -> function is
// stable); output now written as FLOAT32 (reference file's declared output dtype). The
// ~0.37 absmax of rounds 2/3 matches packed-bf16-pairs-read-as-f32 garbage (~|0.3| range).
// Inputs dtype-sniffed per tensor; inputs routed by size class (defensive, identity under
// documented dict order).

__device__ __forceinline__ float bf2f(unsigned short u) {
    unsigned int x = ((unsigned int)u) << 16;
    return __builtin_bit_cast(float, x);
}

// bf16 data: ~100% of 16-bit words have zero or sane exponent field.
// f32 data read as words: ~62% (low halves uniform). Deterministic -> uniform.
__device__ __forceinline__ bool detect_bf16(const void* p, int nwords) {
    const unsigned short* w = (const unsigned short*)p;
    int sane = 0;
    for (int i = 0; i < nwords; ++i) {
        unsigned e = (w[i] >> 7) & 0xFF;
        sane += (e == 0 || (e >= 0x60 && e <= 0x9F)) ? 1 : 0;
    }
    return sane * 10 >= nwords * 9;
}

__device__ __forceinline__ float load_in(const void* p, long idx, bool isbf16) {
    return isbf16 ? bf2f(((const unsigned short*)p)[idx]) : ((const float*)p)[idx];
}

// ---------------- Wo_sum[64][1024] (f32) ----------------
__global__ __launch_bounds__(256) void prep_wosum(const void* __restrict__ Wo,
                                                  float* __restrict__ wosum) {
    int id = blockIdx.x * 256 + threadIdx.x;   // 65536
    bool wb = detect_bf16(Wo, 256);
    int d = id >> 10, n = id & 1023;
    float s = 0.f;
#pragma unroll
    for (int h = 0; h < 16; ++h) s += load_in(Wo, (long)(h * 64 + d) * 1024 + n, wb);
    wosum[id] = s;
}

// ---------------- projections: q/k/v[16384][64] f32, row-major ----------------
// grid (4096, 3) x 256. Thread t: row = bx*4 + (t>>6), col = t&63.
__global__ __launch_bounds__(256) void proj_s(
    const void* __restrict__ X0, const void* __restrict__ X1, const void* __restrict__ X2,
    const void* __restrict__ bq, const void* __restrict__ bk, const void* __restrict__ bv,
    const void* __restrict__ Wq, const void* __restrict__ Wk, const void* __restrict__ Wv,
    float* __restrict__ qo, float* __restrict__ ko, float* __restrict__ vo) {
    int p = blockIdx.y;
    const void* X    = (p == 0) ? X0 : (p == 1) ? X1 : X2;
    const void* W    = (p == 0) ? Wq : (p == 1) ? Wk : Wv;
    const void* bias = (p == 0) ? bq : (p == 1) ? bk : bv;
    float* out       = (p == 0) ? qo : (p == 1) ? ko : vo;
    bool xb = detect_bf16(X, 256);
    bool wb = detect_bf16(W, 256);
    bool bb = detect_bf16(bias, 64);
    int t = threadIdx.x;
    int rl = t >> 6, col = t & 63;
    long row = (long)blockIdx.x * 4 + rl;
    float a = load_in(bias, col, bb);
    for (int k2 = 0; k2 < 1024; ++k2)
        a += load_in(X, row * 1024 + k2, xb) * load_in(W, (long)k2 * 64 + col, wb);
    out[row * 64 + col] = a;
}

// ---------------- attention: one block per (batch, q-row) ----------------
__global__ __launch_bounds__(256) void attn_s(const float* __restrict__ q,
                                              const float* __restrict__ k,
                                              const float* __restrict__ v,
                                              float* __restrict__ ctx) {
    int b = blockIdx.y, qi = blockIdx.x;
    long row = (long)b * 2048 + qi;
    __shared__ float sc[2048];
    __shared__ float red[256];
    __shared__ float qs[64];
    __shared__ float op[4][64];
    int t = threadIdx.x;
    if (t < 64) qs[t] = q[row * 64 + t];
    __syncthreads();
    float lm = -INFINITY;
    for (int jj = t; jj < 2048; jj += 256) {
        const float* kr = k + ((long)b * 2048 + jj) * 64;
        float a = 0.f;
#pragma unroll
        for (int d = 0; d < 64; ++d) a += qs[d] * kr[d];
        a *= 0.125f;                    // / sqrt(64)
        sc[jj] = a;
        lm = fmaxf(lm, a);
    }
    red[t] = lm;
    __syncthreads();
    for (int s = 128; s > 0; s >>= 1) {
        if (t < s) red[t] = fmaxf(red[t], red[t + s]);
        __syncthreads();
    }
    float m = red[0];
    __syncthreads();
    float ls = 0.f;
    for (int jj = t; jj < 2048; jj += 256) {
        float pv = __expf(sc[jj] - m);
        sc[jj] = pv;
        ls += pv;
    }
    red[t] = ls;
    __syncthreads();
    for (int s = 128; s > 0; s >>= 1) {
        if (t < s) red[t] += red[t + s];
        __syncthreads();
    }
    float invL = 1.f / red[0];
    // PV: group g (t>>6) covers keys [g*512,(g+1)*512), dim d = t&63 (coalesced v reads)
    int d = t & 63, g = t >> 6;
    float a = 0.f;
    for (int jj = g * 512; jj < g * 512 + 512; ++jj)
        a += sc[jj] * v[((long)b * 2048 + jj) * 64 + d];
    op[g][d] = a;
    __syncthreads();
    if (t < 64)
        ctx[row * 64 + t] = (op[0][t] + op[1][t] + op[2][t] + op[3][t]) * invL;
}

// ---------------- output: out[16384][1024] f32 = ctx @ Wo_sum + bo ----------------
__global__ __launch_bounds__(256) void out_s(const float* __restrict__ ctx,
                                             const float* __restrict__ wosum,
                                             const void* __restrict__ bo,
                                             float* __restrict__ out) {
    long row = blockIdx.x;
    __shared__ float cr[64];
    int t = threadIdx.x;
    bool bob = detect_bf16(bo, 256);
    if (t < 64) cr[t] = ctx[row * 64 + t];
    __syncthreads();
    for (int c = t; c < 1024; c += 256) {
        float a = load_in(bo, c, bob);
#pragma unroll
        for (int d = 0; d < 64; ++d) a += cr[d] * wosum[d * 1024 + c];
        out[row * 1024 + c] = a;
    }
}

extern "C" void kernel_launch(void* const* d_in, const int* in_sizes, int n_in,
                              void* d_out, int out_size, void* d_ws, size_t ws_size,
                              hipStream_t stream) {
    // Defensive routing by size class (identity if inputs are in dict order):
    // 16777216 -> query,key,value ; 65536 -> Wq,Wk,Wv ; 64 -> bq,bk,bv ;
    // 1048576 -> Wo ; 1024 -> bo. in_sizes are element counts (dtype-independent).
    const void* big[3] = {0, 0, 0};  int nbig = 0;
    const void* w64k[3] = {0, 0, 0}; int nw = 0;
    const void* b64[3] = {0, 0, 0};  int nb = 0;
    const void* Wo = 0; const void* bo = 0;
    for (int i = 0; i < n_in; ++i) {
        int s = in_sizes[i];
        if (s == 16777216 && nbig < 3)     big[nbig++] = d_in[i];
        else if (s == 65536 && nw < 3)     w64k[nw++] = d_in[i];
        else if (s == 64 && nb < 3)        b64[nb++] = d_in[i];
        else if (s == 1048576)             Wo = d_in[i];
        else if (s == 1024)                bo = d_in[i];
    }
    const void* query = big[0]  ? big[0]  : d_in[0];
    const void* key   = big[1]  ? big[1]  : d_in[1];
    const void* value = big[2]  ? big[2]  : d_in[2];
    const void* Wq    = w64k[0] ? w64k[0] : d_in[3];
    const void* Wk    = w64k[1] ? w64k[1] : d_in[5];
    const void* Wv    = w64k[2] ? w64k[2] : d_in[7];
    const void* bq    = b64[0]  ? b64[0]  : d_in[4];
    const void* bk    = b64[1]  ? b64[1]  : d_in[6];
    const void* bv    = b64[2]  ? b64[2]  : d_in[8];
    if (!Wo) Wo = d_in[9];
    if (!bo) bo = d_in[10];
    float* out = (float*)d_out;

    char* ws = (char*)d_ws;
    float* wosum = (float*)(ws);                      // 256 KB
    float* q     = (float*)(ws + 1048576);            // 4 MB
    float* k     = (float*)(ws + 1048576 + 4194304);  // 4 MB
    float* v     = (float*)(ws + 1048576 + 2*4194304);// 4 MB
    float* ctx   = (float*)(ws + 1048576 + 3*4194304);// 4 MB

    hipLaunchKernelGGL(prep_wosum, dim3(256),       dim3(256), 0, stream, Wo, wosum);
    hipLaunchKernelGGL(proj_s,     dim3(4096, 3),   dim3(256), 0, stream,
                       query, key, value, bq, bk, bv, Wq, Wk, Wv, q, k, v);
    hipLaunchKernelGGL(attn_s,     dim3(2048, 8),   dim3(256), 0, stream, q, k, v, ctx);
    hipLaunchKernelGGL(out_s,      dim3(16384),     dim3(256), 0, stream, ctx, wosum, bo, out);
}